// Round 2
// baseline (27.759 us; speedup 1.0000x reference)
//
#include <hip/hip_runtime.h>

#define H_STEPS 200
#define DT 0.01f
#define K_SPRING 100.0f
#define ROWS 256            // batch rows per block (= block size)
#define CW 32               // chunk width: timesteps staged per chunk
#define WORDS_PER_WAVE 2048 // 64 rows * 32 words
#define LDSW (ROWS * CW)    // words per LDS buffer

__device__ __forceinline__ void step(float u, float& x1, float& v1,
                                     float& x2, float& v2) {
    float pen     = x1 + 1.0f - x2;
    float contact = fmaxf(pen, 0.0f);
    float Fc      = -K_SPRING * contact;
    float F1      = u + Fc - v1;      // C = 1
    float F2      = -Fc - v2;
    v1 += F1 * DT;
    v2 += F2 * DT;
    x1 += v1 * DT;
    x2 += v2 * DT;
}

// Wave-local staging: wave w loads rows [w*64, w*64+64) of this block's tile.
// global_load_lds writes LDS linearly (uniform base + lane*4), so the swizzle
// (t ^ (row&31)) is applied to the per-lane GLOBAL source address; the compute
// phase reads word tid*32 + (k ^ (tid&31)) -> bank k^(tid&31): 2 lanes/bank,
// conflict-free.
__device__ __forceinline__ void issue_chunk(const float* __restrict__ u_seq,
                                            float* lbuf, int b0, int wave,
                                            int lane, int t0) {
    const int rb = wave * 64 + (lane >> 5);
    const int tl = lane & 31;
    #pragma unroll
    for (int j = 0; j < 32; ++j) {
        const int r = rb + j * 2;                 // row within block tile
        int tg = t0 + (tl ^ (r & 31));            // swizzled timestep
        tg = tg < H_STEPS ? tg : (H_STEPS - 1);   // clamp tail (dup addr, free)
        const float* g = u_seq + (size_t)(b0 + r) * H_STEPS + tg;
        float* l = lbuf + wave * WORDS_PER_WAVE + j * 64;  // wave-uniform base
        __builtin_amdgcn_global_load_lds(
            (const __attribute__((address_space(1))) void*)g,
            (__attribute__((address_space(3))) void*)l, 4, 0, 0);
    }
}

__global__ __launch_bounds__(ROWS)
void pushing_env_kernel(const float* __restrict__ u_seq,
                        const float* __restrict__ x1_0,
                        const float* __restrict__ v1_0,
                        const float* __restrict__ x2_0,
                        const float* __restrict__ v2_0,
                        const float* __restrict__ goal,
                        float* __restrict__ out, int B) {
    __shared__ float lds[2][LDSW];   // 2 x 32 KB double buffer
    const int tid  = threadIdx.x;
    const int b0   = blockIdx.x * ROWS;
    const int b    = b0 + tid;
    const int wave = tid >> 6;
    const int lane = tid & 63;
    const int sw   = tid & 31;

    float x1 = x1_0[b];
    float v1 = v1_0[b];
    float x2 = x2_0[b];
    float v2 = v2_0[b];
    const float g = goal[0];

    issue_chunk(u_seq, &lds[0][0], b0, wave, lane, 0);

    // 6 full chunks of 32 steps; chunk 6 (8 steps) handled in epilogue.
    // No __syncthreads: staging is wave-local; counted vmcnt self-paces.
    for (int c = 0; c < 6; ++c) {
        issue_chunk(u_seq, &lds[(c + 1) & 1][0], b0, wave, lane, (c + 1) * CW);
        asm volatile("s_waitcnt vmcnt(32)" ::: "memory");  // chunk c landed
        const float* lb = &lds[c & 1][tid * CW];
        #pragma unroll
        for (int k = 0; k < CW; ++k)
            step(lb[k ^ sw], x1, v1, x2, v2);
        asm volatile("" ::: "memory");  // pin order: reads before next overwrite
    }
    asm volatile("s_waitcnt vmcnt(0)" ::: "memory");  // chunk 6 landed
    {
        const float* lb = &lds[0][tid * CW];  // chunk 6 lives in buffer 0
        #pragma unroll
        for (int k = 0; k < 8; ++k)
            step(lb[k ^ sw], x1, v1, x2, v2);
    }

    float d = x2 - g;
    out[b]         = d * d;   // loss
    out[B + b]     = x1;
    out[2 * B + b] = x2;
}

extern "C" void kernel_launch(void* const* d_in, const int* in_sizes, int n_in,
                              void* d_out, int out_size, void* d_ws, size_t ws_size,
                              hipStream_t stream) {
    const float* u_seq = (const float*)d_in[0];
    const float* x1_0  = (const float*)d_in[1];
    const float* v1_0  = (const float*)d_in[2];
    const float* x2_0  = (const float*)d_in[3];
    const float* v2_0  = (const float*)d_in[4];
    const float* goal  = (const float*)d_in[5];
    float* out = (float*)d_out;

    const int B = in_sizes[1];  // 131072
    const int grid = B / ROWS;  // 512 blocks x 256 threads
    pushing_env_kernel<<<grid, ROWS, 0, stream>>>(u_seq, x1_0, v1_0, x2_0,
                                                  v2_0, goal, out, B);
}

// Round 3
// 27.024 us; speedup vs baseline: 1.0272x; 1.0272x over previous
//
#include <hip/hip_runtime.h>

#define H_STEPS 200
#define DT 0.01f
#define K_SPRING 100.0f
#define ROWS 256            // batch rows per block (= block size, 4 waves)
#define CW 32               // timesteps staged per chunk
#define WWORDS 2048         // per-wave buffer words (64 rows * 32 words)
#define LDSW (4 * WWORDS)   // per-buffer words (4 waves)

__device__ __forceinline__ void step(float u, float& x1, float& v1,
                                     float& x2, float& v2) {
    float pen     = x1 + 1.0f - x2;
    float contact = fmaxf(pen, 0.0f);
    float Fc      = -K_SPRING * contact;
    float F1      = u + Fc - v1;      // C = 1
    float F2      = -Fc - v2;
    v1 += F1 * DT;
    v2 += F2 * DT;
    x1 += v1 * DT;
    x2 += v2 * DT;
}

// Stage one 32-timestep chunk for this wave's 64 rows using 8 width-16
// global_load_lds instructions. Instruction j: lane i reads 16B (one qword =
// 4 floats) of row j*8+(i&7); qword slot (i>>3) holds global qword
// (i>>3)^(row&7)  -- XOR swizzle applied on the GLOBAL address (LDS dest is
// linear, wave-uniform base + lane*16). Per instruction the wave touches
// 8 rows x 128B contiguous.
__device__ __forceinline__ void issue_chunk(const float* __restrict__ u_seq,
                                            float* lbuf, int b0, int wave,
                                            int lane, int t0) {
    const int rg   = lane & 7;   // row within 8-row group
    const int slot = lane >> 3;  // qword slot 0..7
    #pragma unroll
    for (int j = 0; j < 8; ++j) {
        const int rl = wave * 64 + j * 8 + rg;       // row within block tile
        const int qg = slot ^ (rl & 7);              // swizzled global qword
        int g = t0 + qg * 4;                         // global word index
        g = g <= H_STEPS - 4 ? g : H_STEPS - 4;      // clamp tail (dup, safe)
        const float* gp = u_seq + (size_t)(b0 + rl) * H_STEPS + g;
        float* lp = lbuf + wave * WWORDS + j * 256;  // wave-uniform base
        __builtin_amdgcn_global_load_lds(
            (const __attribute__((address_space(1))) void*)gp,
            (__attribute__((address_space(3))) void*)lp, 16, 0, 0);
    }
}

__global__ __launch_bounds__(ROWS)
void pushing_env_kernel(const float* __restrict__ u_seq,
                        const float* __restrict__ x1_0,
                        const float* __restrict__ v1_0,
                        const float* __restrict__ x2_0,
                        const float* __restrict__ v2_0,
                        const float* __restrict__ goal,
                        float* __restrict__ out, int B) {
    __shared__ float lds[2][LDSW];   // 2 x 32 KB double buffer
    const int tid  = threadIdx.x;
    const int b0   = blockIdx.x * ROWS;
    const int b    = b0 + tid;
    const int wave = tid >> 6;
    const int rl   = tid & 63;       // this thread's row within its wave
    const int m    = rl & 7;         // swizzle mask

    float x1 = x1_0[b];
    float v1 = v1_0[b];
    float x2 = x2_0[b];
    float v2 = v2_0[b];
    const float g = goal[0];

    // This thread's LDS row base (in float4 units): wave buf + row-group +
    // row-in-group offset. Word base = wave*2048 + (rl>>3)*256 + (rl&7)*4.
    const int f4base = (wave * WWORDS + (rl >> 3) * 256 + m * 4) >> 2;

    issue_chunk(u_seq, &lds[0][0], b0, wave, tid & 63, 0);

    // 6 full chunks; chunk 6 (8 steps) in epilogue. Staging is wave-local:
    // counted vmcnt self-paces, no __syncthreads needed.
    for (int c = 0; c < 6; ++c) {
        issue_chunk(u_seq, &lds[(c + 1) & 1][0], b0, wave, tid & 63,
                    (c + 1) * CW);
        asm volatile("s_waitcnt vmcnt(8)" ::: "memory");   // chunk c landed
        const float4* lf = reinterpret_cast<const float4*>(&lds[c & 1][0]);
        #pragma unroll
        for (int q = 0; q < 8; ++q) {
            float4 u4 = lf[f4base + ((q ^ m) << 3)];
            step(u4.x, x1, v1, x2, v2);
            step(u4.y, x1, v1, x2, v2);
            step(u4.z, x1, v1, x2, v2);
            step(u4.w, x1, v1, x2, v2);
        }
        asm volatile("" ::: "memory");  // pin: reads retire before next issue
    }
    asm volatile("s_waitcnt vmcnt(0)" ::: "memory");       // chunk 6 landed
    {
        const float4* lf = reinterpret_cast<const float4*>(&lds[0][0]);
        #pragma unroll
        for (int q = 0; q < 2; ++q) {
            float4 u4 = lf[f4base + ((q ^ m) << 3)];
            step(u4.x, x1, v1, x2, v2);
            step(u4.y, x1, v1, x2, v2);
            step(u4.z, x1, v1, x2, v2);
            step(u4.w, x1, v1, x2, v2);
        }
    }

    float d = x2 - g;
    out[b]         = d * d;   // loss
    out[B + b]     = x1;
    out[2 * B + b] = x2;
}

extern "C" void kernel_launch(void* const* d_in, const int* in_sizes, int n_in,
                              void* d_out, int out_size, void* d_ws, size_t ws_size,
                              hipStream_t stream) {
    const float* u_seq = (const float*)d_in[0];
    const float* x1_0  = (const float*)d_in[1];
    const float* v1_0  = (const float*)d_in[2];
    const float* x2_0  = (const float*)d_in[3];
    const float* v2_0  = (const float*)d_in[4];
    const float* goal  = (const float*)d_in[5];
    float* out = (float*)d_out;

    const int B = in_sizes[1];  // 131072
    const int grid = B / ROWS;  // 512 blocks x 256 threads
    pushing_env_kernel<<<grid, ROWS, 0, stream>>>(u_seq, x1_0, v1_0, x2_0,
                                                  v2_0, goal, out, B);
}

// Round 4
// 23.788 us; speedup vs baseline: 1.1669x; 1.1361x over previous
//
#include <hip/hip_runtime.h>

#define H_STEPS 200
#define DT 0.01f
#define K_SPRING 100.0f
#define NQ (H_STEPS / 4)   // 50 float4 per row

__device__ __forceinline__ void step(float u, float& x1, float& v1,
                                     float& x2, float& v2) {
    float pen     = x1 + 1.0f - x2;
    float contact = fmaxf(pen, 0.0f);
    float Fc      = -K_SPRING * contact;
    float F1      = u + Fc - v1;      // C = 1
    float F2      = -Fc - v2;
    v1 += F1 * DT;
    v2 += F2 * DT;
    x1 += v1 * DT;
    x2 += v2 * DT;
}

// One thread per batch row. The entire 800B row is prefetched into 200 VGPRs
// (50 float4, fully unrolled, static indices -> registers, no scratch).
// All 50 loads issue before any use; the compiler's per-use counted vmcnt
// gives a ~50-deep memory pipeline per wave (~50KB in flight), maximizing MLP
// for the latency-bound 2-waves/SIMD regime this problem is stuck in.
__global__ __launch_bounds__(256, 2)   // 2 waves/EU -> 256-VGPR budget
void pushing_env_kernel(const float* __restrict__ u_seq,
                        const float* __restrict__ x1_0,
                        const float* __restrict__ v1_0,
                        const float* __restrict__ x2_0,
                        const float* __restrict__ v2_0,
                        const float* __restrict__ goal,
                        float* __restrict__ out, int B) {
    int b = blockIdx.x * blockDim.x + threadIdx.x;

    float x1 = x1_0[b];
    float v1 = v1_0[b];
    float x2 = x2_0[b];
    float v2 = v2_0[b];
    const float g = goal[0];

    const float4* u = reinterpret_cast<const float4*>(u_seq + (size_t)b * H_STEPS);

    float4 r[NQ];
    #pragma unroll
    for (int q = 0; q < NQ; ++q)
        r[q] = u[q];                 // all 50 loads issued up front

    #pragma unroll
    for (int q = 0; q < NQ; ++q) {
        step(r[q].x, x1, v1, x2, v2);
        step(r[q].y, x1, v1, x2, v2);
        step(r[q].z, x1, v1, x2, v2);
        step(r[q].w, x1, v1, x2, v2);
    }

    float d = x2 - g;
    out[b]         = d * d;   // loss
    out[B + b]     = x1;
    out[2 * B + b] = x2;
}

extern "C" void kernel_launch(void* const* d_in, const int* in_sizes, int n_in,
                              void* d_out, int out_size, void* d_ws, size_t ws_size,
                              hipStream_t stream) {
    const float* u_seq = (const float*)d_in[0];
    const float* x1_0  = (const float*)d_in[1];
    const float* v1_0  = (const float*)d_in[2];
    const float* x2_0  = (const float*)d_in[3];
    const float* v2_0  = (const float*)d_in[4];
    const float* goal  = (const float*)d_in[5];
    float* out = (float*)d_out;

    const int B = in_sizes[1];  // 131072
    const int block = 256;
    const int grid = B / block; // 512 blocks
    pushing_env_kernel<<<grid, block, 0, stream>>>(u_seq, x1_0, v1_0, x2_0,
                                                   v2_0, goal, out, B);
}